// Round 6
// baseline (839.160 us; speedup 1.0000x reference)
//
#include <hip/hip_runtime.h>

#define NN   50000
#define E0   800000
#define ET   850000
#define FIN  166
#define KP1  192
#define HID  64
#define NH   8
#define F1   512
#define SCHUNK 52
#define DEGPAD (1024*SCHUNK)
#define GRPS 12500            // 50000/4 nodes per block
#define BLKS_PER_PHASE (GRPS*8)

typedef __attribute__((ext_vector_type(8))) short short8;
typedef __attribute__((ext_vector_type(4))) float f32x4;
typedef __attribute__((ext_vector_type(4))) int int4v;
typedef unsigned short ush;

__device__ __forceinline__ float bf2f(unsigned short u){
  unsigned int x = ((unsigned int)u) << 16;
  return __builtin_bit_cast(float, x);
}
__device__ __forceinline__ unsigned short f2bf(float f){
  unsigned int x = __builtin_bit_cast(unsigned int, f);
  x += 0x7FFFu + ((x >> 16) & 1u);
  return (unsigned short)(x >> 16);
}

// ---- fused prep: pad/convert x, transpose+convert W1,W2, dst-degree histogram ----
__global__ __launch_bounds__(256) void k_prep_all(const float* __restrict__ x,
                                                  const float* __restrict__ W1,
                                                  const float* __restrict__ W2,
                                                  const int* __restrict__ ei,
                                                  ush* __restrict__ xpad,
                                                  ush* __restrict__ W1t,
                                                  ush* __restrict__ W2t,
                                                  int* __restrict__ deg){
  const int T0 = NN*KP1;
  const int T1 = T0 + 512*KP1;
  const int T2 = T1 + HID*F1;
  const int T3 = T2 + ET;
  int i = blockIdx.x*256 + threadIdx.x;
  if (i >= T3) return;
  if (i < T0){
    int n = i / KP1, k = i % KP1;
    xpad[i] = f2bf(k < FIN ? x[(size_t)n*FIN + k] : 0.f);
  } else if (i < T1){
    int j = i - T0; int col = j / KP1, k = j % KP1;
    W1t[j] = f2bf(k < FIN ? W1[(size_t)k*512 + col] : 0.f);
  } else if (i < T2){
    int j = i - T1; int col = j / F1, k = j % F1;
    W2t[j] = f2bf(W2[(size_t)k*HID + col]);
  } else {
    int e = i - T2;
    int dst = (e < E0) ? ei[E0 + e] : (e - E0);
    atomicAdd(&deg[dst], 1);
  }
}

// ---- exclusive scan of deg -> offs[NN+1], single block, int4 loads ----
__global__ __launch_bounds__(1024) void k_scan(const int* __restrict__ deg,
                                               int* __restrict__ offs){
  __shared__ int sums[1024];
  int t = threadIdx.x;
  int base = t * SCHUNK;
  int4v v[13];
  int loc = 0;
  #pragma unroll
  for (int c = 0; c < 13; c++){
    v[c] = *(const int4v*)(deg + base + c*4);
    loc += v[c].x + v[c].y + v[c].z + v[c].w;
  }
  sums[t] = loc; __syncthreads();
  for (int off = 1; off < 1024; off <<= 1){
    int s = (t >= off) ? sums[t - off] : 0;
    __syncthreads();
    sums[t] += s;
    __syncthreads();
  }
  int run = sums[t] - loc;
  #pragma unroll
  for (int c = 0; c < 13; c++){
    int i0 = base + c*4;
    if (i0 + 0 < NN) offs[i0 + 0] = run;  run += v[c].x;
    if (i0 + 1 < NN) offs[i0 + 1] = run;  run += v[c].y;
    if (i0 + 2 < NN) offs[i0 + 2] = run;  run += v[c].z;
    if (i0 + 3 < NN) offs[i0 + 3] = run;  run += v[c].w;
  }
  if (t == 1023) offs[NN] = sums[1023];
}

// ---- scatter edges into CSR-by-dst ----
__global__ __launch_bounds__(256) void k_scatter(const int* __restrict__ ei,
                                                 const int* __restrict__ offs,
                                                 int* __restrict__ cur,
                                                 int* __restrict__ esrc){
  for (int e = blockIdx.x*256 + threadIdx.x; e < ET; e += gridDim.x*256){
    int src, dst;
    if (e < E0){ src = ei[e]; dst = ei[E0 + e]; }
    else       { src = e - E0; dst = src; }
    int pos = offs[dst] + atomicAdd(&cur[dst], 1);
    esrc[pos] = src;
  }
}

// ---- GEMM1: xpad[NN,192] @ W1t^T -> xp1 bf16 [NN,512]; fused per-head logits ----
__global__ __launch_bounds__(256) void k_gemm1(const ush* __restrict__ xpad,
                                               const ush* __restrict__ W1t,
                                               const float* __restrict__ a_s,
                                               const float* __restrict__ a_d,
                                               ush* __restrict__ xp1,
                                               float* __restrict__ als,
                                               float* __restrict__ ald){
  __shared__ ush As[128][40];
  __shared__ ush Bs[128][40];
  const int m0 = blockIdx.x*128, n0 = blockIdx.y*128;
  const int t = threadIdx.x, wid = t>>6, l = t&63;
  const int wr = wid>>1, wc = wid&1;
  const int lr = l&15, ksl = (l>>4)*8;
  const int srow = t>>1, sc = (t&1)*16;

  f32x4 acc[4][4];
  #pragma unroll
  for (int m = 0; m < 4; m++)
    #pragma unroll
    for (int n = 0; n < 4; n++)
      #pragma unroll
      for (int j = 0; j < 4; j++) acc[m][n][j] = 0.f;

  const int gr = m0 + srow;
  const ush* Ap = xpad + (size_t)gr*KP1 + sc;
  const ush* Bp = W1t + (size_t)(n0 + srow)*KP1 + sc;

  for (int s = 0; s < 6; s++){
    const int kk = s*32;
    short8 a0, a1;
    #pragma unroll
    for (int j = 0; j < 8; j++){ a0[j] = 0; a1[j] = 0; }
    if (gr < NN){ a0 = *(const short8*)(Ap + kk); a1 = *(const short8*)(Ap + kk + 8); }
    short8 b0 = *(const short8*)(Bp + kk);
    short8 b1 = *(const short8*)(Bp + kk + 8);
    *(short8*)&As[srow][sc]   = a0;
    *(short8*)&As[srow][sc+8] = a1;
    *(short8*)&Bs[srow][sc]   = b0;
    *(short8*)&Bs[srow][sc+8] = b1;
    __syncthreads();
    short8 af[4], bfr[4];
    #pragma unroll
    for (int m = 0; m < 4; m++) af[m]  = *(const short8*)&As[wr*64 + m*16 + lr][ksl];
    #pragma unroll
    for (int n = 0; n < 4; n++) bfr[n] = *(const short8*)&Bs[wc*64 + n*16 + lr][ksl];
    #pragma unroll
    for (int m = 0; m < 4; m++)
      #pragma unroll
      for (int n = 0; n < 4; n++)
        acc[m][n] = __builtin_amdgcn_mfma_f32_16x16x32_bf16(af[m], bfr[n], acc[m][n], 0, 0, 0);
    __syncthreads();
  }

  #pragma unroll
  for (int m = 0; m < 4; m++)
    #pragma unroll
    for (int n = 0; n < 4; n++)
      #pragma unroll
      for (int j = 0; j < 4; j++){
        int row = m0 + wr*64 + m*16 + (l>>4)*4 + j;
        int col = n0 + wc*64 + n*16 + lr;
        if (row < NN) xp1[(size_t)row*F1 + col] = f2bf(acc[m][n][j]);
      }

  const int head = blockIdx.y*2 + wc;
  float asv[4], adv[4];
  #pragma unroll
  for (int n = 0; n < 4; n++){
    asv[n] = a_s[head*64 + n*16 + lr];
    adv[n] = a_d[head*64 + n*16 + lr];
  }
  #pragma unroll
  for (int m = 0; m < 4; m++)
    #pragma unroll
    for (int j = 0; j < 4; j++){
      float ps = 0.f, pd = 0.f;
      #pragma unroll
      for (int n = 0; n < 4; n++){
        ps = fmaf(acc[m][n][j], asv[n], ps);
        pd = fmaf(acc[m][n][j], adv[n], pd);
      }
      #pragma unroll
      for (int o = 1; o < 16; o <<= 1){
        ps += __shfl_xor(ps, o, 64);
        pd += __shfl_xor(pd, o, 64);
      }
      if (lr == 0){
        int row = m0 + wr*64 + m*16 + (l>>4)*4 + j;
        if (row < NN){
          als[(size_t)row*NH + head] = fminf(fmaxf(ps, -30.f), 30.f);
          ald[(size_t)row*NH + head] = fminf(fmaxf(pd, -30.f), 30.f);
        }
      }
    }
}

// ---- GEMM2: h1[NN,512] @ W2t^T -> xp2 bf16 [NN,64]; fused logits (1 head) ----
__global__ __launch_bounds__(256) void k_gemm2(const ush* __restrict__ h1,
                                               const ush* __restrict__ W2t,
                                               const float* __restrict__ a_s,
                                               const float* __restrict__ a_d,
                                               ush* __restrict__ xp2,
                                               float* __restrict__ als,
                                               float* __restrict__ ald){
  __shared__ ush As[128][40];
  __shared__ ush Bs[64][40];
  const int m0 = blockIdx.x*128;
  const int t = threadIdx.x, wid = t>>6, l = t&63;
  const int lr = l&15, ksl = (l>>4)*8;
  const int srow = t>>1, sc = (t&1)*16;

  f32x4 acc[2][4];
  #pragma unroll
  for (int m = 0; m < 2; m++)
    #pragma unroll
    for (int n = 0; n < 4; n++)
      #pragma unroll
      for (int j = 0; j < 4; j++) acc[m][n][j] = 0.f;

  const int gr = m0 + srow;
  const ush* Ap = h1 + (size_t)gr*F1 + sc;
  const ush* Bp = W2t + (size_t)srow*F1 + sc;

  for (int s = 0; s < 16; s++){
    const int kk = s*32;
    short8 a0, a1;
    #pragma unroll
    for (int j = 0; j < 8; j++){ a0[j] = 0; a1[j] = 0; }
    if (gr < NN){ a0 = *(const short8*)(Ap + kk); a1 = *(const short8*)(Ap + kk + 8); }
    *(short8*)&As[srow][sc]   = a0;
    *(short8*)&As[srow][sc+8] = a1;
    if (t < 128){
      short8 b0 = *(const short8*)(Bp + kk);
      short8 b1 = *(const short8*)(Bp + kk + 8);
      *(short8*)&Bs[srow][sc]   = b0;
      *(short8*)&Bs[srow][sc+8] = b1;
    }
    __syncthreads();
    short8 af[2], bfr[4];
    #pragma unroll
    for (int m = 0; m < 2; m++) af[m]  = *(const short8*)&As[wid*32 + m*16 + lr][ksl];
    #pragma unroll
    for (int n = 0; n < 4; n++) bfr[n] = *(const short8*)&Bs[n*16 + lr][ksl];
    #pragma unroll
    for (int m = 0; m < 2; m++)
      #pragma unroll
      for (int n = 0; n < 4; n++)
        acc[m][n] = __builtin_amdgcn_mfma_f32_16x16x32_bf16(af[m], bfr[n], acc[m][n], 0, 0, 0);
    __syncthreads();
  }

  #pragma unroll
  for (int m = 0; m < 2; m++)
    #pragma unroll
    for (int n = 0; n < 4; n++)
      #pragma unroll
      for (int j = 0; j < 4; j++){
        int row = m0 + wid*32 + m*16 + (l>>4)*4 + j;
        int col = n*16 + lr;
        if (row < NN) xp2[(size_t)row*HID + col] = f2bf(acc[m][n][j]);
      }

  float asv[4], adv[4];
  #pragma unroll
  for (int n = 0; n < 4; n++){
    asv[n] = a_s[n*16 + lr];
    adv[n] = a_d[n*16 + lr];
  }
  #pragma unroll
  for (int m = 0; m < 2; m++)
    #pragma unroll
    for (int j = 0; j < 4; j++){
      float ps = 0.f, pd = 0.f;
      #pragma unroll
      for (int n = 0; n < 4; n++){
        ps = fmaf(acc[m][n][j], asv[n], ps);
        pd = fmaf(acc[m][n][j], adv[n], pd);
      }
      #pragma unroll
      for (int o = 1; o < 16; o <<= 1){
        ps += __shfl_xor(ps, o, 64);
        pd += __shfl_xor(pd, o, 64);
      }
      if (lr == 0){
        int row = m0 + wid*32 + m*16 + (l>>4)*4 + j;
        if (row < NN){
          als[row] = fminf(fmaxf(ps, -30.f), 30.f);
          ald[row] = fminf(fmaxf(pd, -30.f), 30.f);
        }
      }
    }
}

// ---- layer-1 aggregation, XCD-pinned feature slices ----
// wave = (node, slice of 32 feats). 16 slices; slice%8 == bid%8 -> pinned to one
// XCD whose 4MB L2 holds the 3.2MB slice; two temporal phases (slice<8, slice>=8).
// Within a sub-chunk: 16 edges x 4 lanes each (16B/lane), one gather instruction.
__global__ __launch_bounds__(256) void k_agg1(const int* __restrict__ offs,
                                              const int* __restrict__ esrc,
                                              const ush* __restrict__ xp1,
                                              const float* __restrict__ als,
                                              const float* __restrict__ ald,
                                              const float* __restrict__ b1,
                                              ush* __restrict__ h1){
  int bid = blockIdx.x;
  int phase = bid / BLKS_PER_PHASE;
  int r = bid - phase*BLKS_PER_PHASE;
  int slice = (r & 7) + (phase << 3);
  int node = (r >> 3)*4 + (threadIdx.x >> 6);
  int l = threadIdx.x & 63;
  int head = slice >> 1;
  int f0 = slice*32 + (l & 3)*8;        // global feature base for this lane
  float ad = ald[node*NH + head];
  int s0 = offs[node], s1 = offs[node+1];

  float acc[8];
  #pragma unroll
  for (int j = 0; j < 8; j++) acc[j] = 0.f;
  float den = 0.f;
  int g = l >> 2;                       // edge group 0..15

  for (int base = s0; base < s1; base += 64){
    int myE = (base + l < s1) ? esrc[base + l] : 0;
    int nsub = min(64, s1 - base);
    for (int sub = 0; sub*16 < nsub; sub++){
      // wt for edges [base+sub*16, +16) computed on lanes 0..15
      int aSrc = __shfl(myE, sub*16 + (l & 15), 64);
      float w_ = 0.f;
      if (l < 16 && base + sub*16 + l < s1){
        float e_ = als[aSrc*NH + head] + ad;
        e_ = fmaxf(e_, 0.2f*e_);
        w_ = __expf(e_);
      }
      int eidx = base + sub*16 + g;
      int gSrc = __shfl(myE, sub*16 + g, 64);
      float wt = __shfl(w_, g, 64);
      if (eidx < s1){
        short8 v = *(const short8*)(xp1 + (size_t)gSrc*F1 + f0);
        den += wt;
        #pragma unroll
        for (int j = 0; j < 8; j++)
          acc[j] = fmaf(wt, bf2f((ush)v[j]), acc[j]);
      }
    }
  }
  // reduce across the 16 edge groups (stride 4,8,16,32)
  #pragma unroll
  for (int o = 4; o < 64; o <<= 1){
    den += __shfl_xor(den, o, 64);
    #pragma unroll
    for (int j = 0; j < 8; j++) acc[j] += __shfl_xor(acc[j], o, 64);
  }
  if (l < 4){
    float inv = 1.f / den;
    short8 ov;
    #pragma unroll
    for (int j = 0; j < 8; j++){
      float o = acc[j]*inv + b1[f0 + j];
      o = o > 0.f ? o : expm1f(o);        // ELU
      ov[j] = (short)f2bf(o);
    }
    *(short8*)(h1 + (size_t)node*F1 + f0) = ov;
  }
}

// ---- layer-2 aggregation (bf16 gather, in-loop weights) + fused classifier ----
__global__ __launch_bounds__(256) void k_agg2(const int* __restrict__ offs,
                                              const int* __restrict__ esrc,
                                              const ush* __restrict__ xp2,
                                              const float* __restrict__ als,
                                              const float* __restrict__ ald,
                                              const float* __restrict__ b2,
                                              const float* __restrict__ Wc1,
                                              const float* __restrict__ bc1,
                                              const float* __restrict__ Wc2,
                                              const float* __restrict__ bc2,
                                              float* __restrict__ out){
  int w = (blockIdx.x*256 + threadIdx.x) >> 6;
  int l = threadIdx.x & 63;
  if (w >= NN) return;
  float ad = ald[w];
  int s0 = offs[w], s1 = offs[w+1];
  float accA = 0.f, accB = 0.f, den = 0.f;

  for (int base = s0; base < s1; base += 64){
    int cnt = min(64, s1 - base);
    int myE = (base + l < s1) ? esrc[base + l] : 0;
    int j = 0;
    for (; j + 4 <= cnt; j += 4){
      int sA = __shfl(myE, j,   64);
      int sB = __shfl(myE, j+1, 64);
      int sC = __shfl(myE, j+2, 64);
      int sD = __shfl(myE, j+3, 64);
      float eA = als[sA] + ad, eB = als[sB] + ad, eC = als[sC] + ad, eD = als[sD] + ad;
      eA = fmaxf(eA, 0.2f*eA); eB = fmaxf(eB, 0.2f*eB);
      eC = fmaxf(eC, 0.2f*eC); eD = fmaxf(eD, 0.2f*eD);
      float wA = __expf(eA), wB = __expf(eB), wC = __expf(eC), wD = __expf(eD);
      float xA = bf2f(xp2[(size_t)sA*HID + l]);
      float xB = bf2f(xp2[(size_t)sB*HID + l]);
      float xC = bf2f(xp2[(size_t)sC*HID + l]);
      float xD = bf2f(xp2[(size_t)sD*HID + l]);
      den += (wA + wB) + (wC + wD);
      accA = fmaf(wA, xA, accA); accB = fmaf(wB, xB, accB);
      accA = fmaf(wC, xC, accA); accB = fmaf(wD, xD, accB);
    }
    for (; j < cnt; j++){
      int sA = __shfl(myE, j, 64);
      float eA = als[sA] + ad;
      eA = fmaxf(eA, 0.2f*eA);
      float wA = __expf(eA);
      den += wA;
      accA = fmaf(wA, bf2f(xp2[(size_t)sA*HID + l]), accA);
    }
  }
  float h2 = (accA + accB) / den + b2[l];
  float r = 0.f;
  #pragma unroll
  for (int k = 0; k < 64; k++){
    float hk = __shfl(h2, k, 64);
    r = fmaf(hk, Wc1[k*HID + l], r);
  }
  r += bc1[l];
  r = fmaxf(r, 0.f);
  float p0 = r * Wc2[l*2 + 0];
  float p1 = r * Wc2[l*2 + 1];
  #pragma unroll
  for (int o = 1; o < 64; o <<= 1){
    p0 += __shfl_xor(p0, o, 64);
    p1 += __shfl_xor(p1, o, 64);
  }
  if (l == 0){
    out[(size_t)w*2 + 0] = p0 + bc2[0];
    out[(size_t)w*2 + 1] = p1 + bc2[1];
  }
}

extern "C" void kernel_launch(void* const* d_in, const int* in_sizes, int n_in,
                              void* d_out, int out_size, void* d_ws, size_t ws_size,
                              hipStream_t stream){
  const float* x   = (const float*)d_in[0];
  const int*   ei  = (const int*)  d_in[1];
  const float* W1  = (const float*)d_in[2];
  const float* as1 = (const float*)d_in[3];
  const float* ad1 = (const float*)d_in[4];
  const float* b1  = (const float*)d_in[5];
  const float* W2  = (const float*)d_in[6];
  const float* as2 = (const float*)d_in[7];
  const float* ad2 = (const float*)d_in[8];
  const float* b2  = (const float*)d_in[9];
  const float* Wc1 = (const float*)d_in[10];
  const float* bc1 = (const float*)d_in[11];
  const float* Wc2 = (const float*)d_in[12];
  const float* bc2 = (const float*)d_in[13];
  float* out = (float*)d_out;

  char* p = (char*)d_ws; size_t off = 0;
  auto alloc = [&](size_t b){ void* r = p + off; off = (off + b + 255) & ~(size_t)255; return r; };
  ush* xpad = (ush*)alloc((size_t)NN*KP1*2);
  ush* W1t  = (ush*)alloc((size_t)512*KP1*2);
  ush* W2t  = (ush*)alloc((size_t)HID*F1*2);
  ush* xp1  = (ush*)alloc((size_t)NN*F1*2);
  ush* h1   = (ush*)alloc((size_t)NN*F1*2);
  ush* xp2  = (ush*)alloc((size_t)NN*HID*2);
  float* als1 = (float*)alloc((size_t)NN*NH*4);
  float* ald1 = (float*)alloc((size_t)NN*NH*4);
  float* als2 = (float*)alloc((size_t)NN*4);
  float* ald2 = (float*)alloc((size_t)NN*4);
  int* deg  = (int*)alloc((size_t)DEGPAD*4);
  int* cur  = (int*)alloc((size_t)NN*4);
  int* offs = (int*)alloc((size_t)(NN+1)*4);
  int* esrc = (int*)alloc((size_t)ET*4);

  hipMemsetAsync(deg, 0, (size_t)DEGPAD*4, stream);
  hipMemsetAsync(cur, 0, (size_t)NN*4, stream);

  const int T3 = NN*KP1 + 512*KP1 + HID*F1 + ET;
  k_prep_all<<<(T3 + 255)/256, 256, 0, stream>>>(x, W1, W2, ei, xpad, W1t, W2t, deg);
  k_scan<<<1, 1024, 0, stream>>>(deg, offs);
  k_scatter<<<(ET + 255)/256, 256, 0, stream>>>(ei, offs, cur, esrc);

  k_gemm1<<<dim3(391, 4), 256, 0, stream>>>(xpad, W1t, as1, ad1, xp1, als1, ald1);
  k_agg1<<<2*BLKS_PER_PHASE, 256, 0, stream>>>(offs, esrc, xp1, als1, ald1, b1, h1);

  k_gemm2<<<391, 256, 0, stream>>>(h1, W2t, as2, ad2, xp2, als2, ald2);
  k_agg2<<<12500, 256, 0, stream>>>(offs, esrc, xp2, als2, ald2, b2, Wc1, bc1, Wc2, bc2, out);
}

// Round 7
// 421.878 us; speedup vs baseline: 1.9891x; 1.9891x over previous
//
#include <hip/hip_runtime.h>

#define NN   50000
#define E0   800000
#define ET   850000
#define FIN  166
#define KP1  192
#define HID  64
#define NH   8
#define F1   512
#define SCHUNK 52
#define DEGPAD (1024*SCHUNK)

typedef __attribute__((ext_vector_type(8))) short short8;
typedef __attribute__((ext_vector_type(4))) float f32x4;
typedef __attribute__((ext_vector_type(4))) int int4v;
typedef unsigned short ush;

__device__ __forceinline__ float bf2f(unsigned short u){
  unsigned int x = ((unsigned int)u) << 16;
  return __builtin_bit_cast(float, x);
}
__device__ __forceinline__ unsigned short f2bf(float f){
  unsigned int x = __builtin_bit_cast(unsigned int, f);
  x += 0x7FFFu + ((x >> 16) & 1u);
  return (unsigned short)(x >> 16);
}

// ---- fused prep: pad/convert x, transpose+convert W1,W2, dst-degree histogram ----
__global__ __launch_bounds__(256) void k_prep_all(const float* __restrict__ x,
                                                  const float* __restrict__ W1,
                                                  const float* __restrict__ W2,
                                                  const int* __restrict__ ei,
                                                  ush* __restrict__ xpad,
                                                  ush* __restrict__ W1t,
                                                  ush* __restrict__ W2t,
                                                  int* __restrict__ deg){
  const int T0 = NN*KP1;
  const int T1 = T0 + 512*KP1;
  const int T2 = T1 + HID*F1;
  const int T3 = T2 + ET;
  int i = blockIdx.x*256 + threadIdx.x;
  if (i >= T3) return;
  if (i < T0){
    int n = i / KP1, k = i % KP1;
    xpad[i] = f2bf(k < FIN ? x[(size_t)n*FIN + k] : 0.f);
  } else if (i < T1){
    int j = i - T0; int col = j / KP1, k = j % KP1;
    W1t[j] = f2bf(k < FIN ? W1[(size_t)k*512 + col] : 0.f);
  } else if (i < T2){
    int j = i - T1; int col = j / F1, k = j % F1;
    W2t[j] = f2bf(W2[(size_t)k*HID + col]);
  } else {
    int e = i - T2;
    int dst = (e < E0) ? ei[E0 + e] : (e - E0);
    atomicAdd(&deg[dst], 1);
  }
}

// ---- exclusive scan of deg -> offs[NN+1], single block, int4 loads ----
__global__ __launch_bounds__(1024) void k_scan(const int* __restrict__ deg,
                                               int* __restrict__ offs){
  __shared__ int sums[1024];
  int t = threadIdx.x;
  int base = t * SCHUNK;
  int4v v[13];
  int loc = 0;
  #pragma unroll
  for (int c = 0; c < 13; c++){
    v[c] = *(const int4v*)(deg + base + c*4);
    loc += v[c].x + v[c].y + v[c].z + v[c].w;
  }
  sums[t] = loc; __syncthreads();
  for (int off = 1; off < 1024; off <<= 1){
    int s = (t >= off) ? sums[t - off] : 0;
    __syncthreads();
    sums[t] += s;
    __syncthreads();
  }
  int run = sums[t] - loc;
  #pragma unroll
  for (int c = 0; c < 13; c++){
    int i0 = base + c*4;
    if (i0 + 0 < NN) offs[i0 + 0] = run;  run += v[c].x;
    if (i0 + 1 < NN) offs[i0 + 1] = run;  run += v[c].y;
    if (i0 + 2 < NN) offs[i0 + 2] = run;  run += v[c].z;
    if (i0 + 3 < NN) offs[i0 + 3] = run;  run += v[c].w;
  }
  if (t == 1023) offs[NN] = sums[1023];
}

// ---- scatter edges into CSR-by-dst ----
__global__ __launch_bounds__(256) void k_scatter(const int* __restrict__ ei,
                                                 const int* __restrict__ offs,
                                                 int* __restrict__ cur,
                                                 int* __restrict__ esrc){
  for (int e = blockIdx.x*256 + threadIdx.x; e < ET; e += gridDim.x*256){
    int src, dst;
    if (e < E0){ src = ei[e]; dst = ei[E0 + e]; }
    else       { src = e - E0; dst = src; }
    int pos = offs[dst] + atomicAdd(&cur[dst], 1);
    esrc[pos] = src;
  }
}

// ---- GEMM1: xpad[NN,192] @ W1t^T -> xp1 bf16 [NN,512]; fused per-head logits ----
__global__ __launch_bounds__(256) void k_gemm1(const ush* __restrict__ xpad,
                                               const ush* __restrict__ W1t,
                                               const float* __restrict__ a_s,
                                               const float* __restrict__ a_d,
                                               ush* __restrict__ xp1,
                                               float* __restrict__ als,
                                               float* __restrict__ ald){
  __shared__ ush As[128][40];
  __shared__ ush Bs[128][40];
  const int m0 = blockIdx.x*128, n0 = blockIdx.y*128;
  const int t = threadIdx.x, wid = t>>6, l = t&63;
  const int wr = wid>>1, wc = wid&1;
  const int lr = l&15, ksl = (l>>4)*8;
  const int srow = t>>1, sc = (t&1)*16;

  f32x4 acc[4][4];
  #pragma unroll
  for (int m = 0; m < 4; m++)
    #pragma unroll
    for (int n = 0; n < 4; n++)
      #pragma unroll
      for (int j = 0; j < 4; j++) acc[m][n][j] = 0.f;

  const int gr = m0 + srow;
  const ush* Ap = xpad + (size_t)gr*KP1 + sc;
  const ush* Bp = W1t + (size_t)(n0 + srow)*KP1 + sc;

  for (int s = 0; s < 6; s++){
    const int kk = s*32;
    short8 a0, a1;
    #pragma unroll
    for (int j = 0; j < 8; j++){ a0[j] = 0; a1[j] = 0; }
    if (gr < NN){ a0 = *(const short8*)(Ap + kk); a1 = *(const short8*)(Ap + kk + 8); }
    short8 b0 = *(const short8*)(Bp + kk);
    short8 b1 = *(const short8*)(Bp + kk + 8);
    *(short8*)&As[srow][sc]   = a0;
    *(short8*)&As[srow][sc+8] = a1;
    *(short8*)&Bs[srow][sc]   = b0;
    *(short8*)&Bs[srow][sc+8] = b1;
    __syncthreads();
    short8 af[4], bfr[4];
    #pragma unroll
    for (int m = 0; m < 4; m++) af[m]  = *(const short8*)&As[wr*64 + m*16 + lr][ksl];
    #pragma unroll
    for (int n = 0; n < 4; n++) bfr[n] = *(const short8*)&Bs[wc*64 + n*16 + lr][ksl];
    #pragma unroll
    for (int m = 0; m < 4; m++)
      #pragma unroll
      for (int n = 0; n < 4; n++)
        acc[m][n] = __builtin_amdgcn_mfma_f32_16x16x32_bf16(af[m], bfr[n], acc[m][n], 0, 0, 0);
    __syncthreads();
  }

  #pragma unroll
  for (int m = 0; m < 4; m++)
    #pragma unroll
    for (int n = 0; n < 4; n++)
      #pragma unroll
      for (int j = 0; j < 4; j++){
        int row = m0 + wr*64 + m*16 + (l>>4)*4 + j;
        int col = n0 + wc*64 + n*16 + lr;
        if (row < NN) xp1[(size_t)row*F1 + col] = f2bf(acc[m][n][j]);
      }

  const int head = blockIdx.y*2 + wc;
  float asv[4], adv[4];
  #pragma unroll
  for (int n = 0; n < 4; n++){
    asv[n] = a_s[head*64 + n*16 + lr];
    adv[n] = a_d[head*64 + n*16 + lr];
  }
  #pragma unroll
  for (int m = 0; m < 4; m++)
    #pragma unroll
    for (int j = 0; j < 4; j++){
      float ps = 0.f, pd = 0.f;
      #pragma unroll
      for (int n = 0; n < 4; n++){
        ps = fmaf(acc[m][n][j], asv[n], ps);
        pd = fmaf(acc[m][n][j], adv[n], pd);
      }
      #pragma unroll
      for (int o = 1; o < 16; o <<= 1){
        ps += __shfl_xor(ps, o, 64);
        pd += __shfl_xor(pd, o, 64);
      }
      if (lr == 0){
        int row = m0 + wr*64 + m*16 + (l>>4)*4 + j;
        if (row < NN){
          als[(size_t)row*NH + head] = fminf(fmaxf(ps, -30.f), 30.f);
          ald[(size_t)row*NH + head] = fminf(fmaxf(pd, -30.f), 30.f);
        }
      }
    }
}

// ---- GEMM2: h1[NN,512] @ W2t^T -> xp2 bf16 [NN,64]; fused logits (1 head) ----
__global__ __launch_bounds__(256) void k_gemm2(const ush* __restrict__ h1,
                                               const ush* __restrict__ W2t,
                                               const float* __restrict__ a_s,
                                               const float* __restrict__ a_d,
                                               ush* __restrict__ xp2,
                                               float* __restrict__ als,
                                               float* __restrict__ ald){
  __shared__ ush As[128][40];
  __shared__ ush Bs[64][40];
  const int m0 = blockIdx.x*128;
  const int t = threadIdx.x, wid = t>>6, l = t&63;
  const int lr = l&15, ksl = (l>>4)*8;
  const int srow = t>>1, sc = (t&1)*16;

  f32x4 acc[2][4];
  #pragma unroll
  for (int m = 0; m < 2; m++)
    #pragma unroll
    for (int n = 0; n < 4; n++)
      #pragma unroll
      for (int j = 0; j < 4; j++) acc[m][n][j] = 0.f;

  const int gr = m0 + srow;
  const ush* Ap = h1 + (size_t)gr*F1 + sc;
  const ush* Bp = W2t + (size_t)srow*F1 + sc;

  for (int s = 0; s < 16; s++){
    const int kk = s*32;
    short8 a0, a1;
    #pragma unroll
    for (int j = 0; j < 8; j++){ a0[j] = 0; a1[j] = 0; }
    if (gr < NN){ a0 = *(const short8*)(Ap + kk); a1 = *(const short8*)(Ap + kk + 8); }
    *(short8*)&As[srow][sc]   = a0;
    *(short8*)&As[srow][sc+8] = a1;
    if (t < 128){
      short8 b0 = *(const short8*)(Bp + kk);
      short8 b1 = *(const short8*)(Bp + kk + 8);
      *(short8*)&Bs[srow][sc]   = b0;
      *(short8*)&Bs[srow][sc+8] = b1;
    }
    __syncthreads();
    short8 af[2], bfr[4];
    #pragma unroll
    for (int m = 0; m < 2; m++) af[m]  = *(const short8*)&As[wid*32 + m*16 + lr][ksl];
    #pragma unroll
    for (int n = 0; n < 4; n++) bfr[n] = *(const short8*)&Bs[n*16 + lr][ksl];
    #pragma unroll
    for (int m = 0; m < 2; m++)
      #pragma unroll
      for (int n = 0; n < 4; n++)
        acc[m][n] = __builtin_amdgcn_mfma_f32_16x16x32_bf16(af[m], bfr[n], acc[m][n], 0, 0, 0);
    __syncthreads();
  }

  #pragma unroll
  for (int m = 0; m < 2; m++)
    #pragma unroll
    for (int n = 0; n < 4; n++)
      #pragma unroll
      for (int j = 0; j < 4; j++){
        int row = m0 + wid*32 + m*16 + (l>>4)*4 + j;
        int col = n*16 + lr;
        if (row < NN) xp2[(size_t)row*HID + col] = f2bf(acc[m][n][j]);
      }

  float asv[4], adv[4];
  #pragma unroll
  for (int n = 0; n < 4; n++){
    asv[n] = a_s[n*16 + lr];
    adv[n] = a_d[n*16 + lr];
  }
  #pragma unroll
  for (int m = 0; m < 2; m++)
    #pragma unroll
    for (int j = 0; j < 4; j++){
      float ps = 0.f, pd = 0.f;
      #pragma unroll
      for (int n = 0; n < 4; n++){
        ps = fmaf(acc[m][n][j], asv[n], ps);
        pd = fmaf(acc[m][n][j], adv[n], pd);
      }
      #pragma unroll
      for (int o = 1; o < 16; o <<= 1){
        ps += __shfl_xor(ps, o, 64);
        pd += __shfl_xor(pd, o, 64);
      }
      if (lr == 0){
        int row = m0 + wid*32 + m*16 + (l>>4)*4 + j;
        if (row < NN){
          als[row] = fminf(fmaxf(ps, -30.f), 30.f);
          ald[row] = fminf(fmaxf(pd, -30.f), 30.f);
        }
      }
    }
}

// ---- layer-1 aggregation: wave per dst; chunked esrc via shfl; 4-way unroll ----
__global__ __launch_bounds__(256) void k_agg1(const int* __restrict__ offs,
                                              const int* __restrict__ esrc,
                                              const ush* __restrict__ xp1,
                                              const float* __restrict__ als,
                                              const float* __restrict__ ald,
                                              const float* __restrict__ b1,
                                              ush* __restrict__ h1,
                                              int nodeBase, int nodeCnt){
  int w = (blockIdx.x*256 + threadIdx.x) >> 6;
  int l = threadIdx.x & 63;
  if (w >= nodeCnt) return;
  w += nodeBase;
  int h = l >> 3;
  int f0 = l * 8;
  float ad = ald[w*NH + h];
  int s0 = offs[w], s1 = offs[w+1];
  float accA[8], accB[8];
  #pragma unroll
  for (int j = 0; j < 8; j++){ accA[j] = 0.f; accB[j] = 0.f; }
  float den = 0.f;

  for (int base = s0; base < s1; base += 64){
    int cnt = min(64, s1 - base);
    int myE = (base + l < s1) ? esrc[base + l] : 0;
    int j = 0;
    for (; j + 4 <= cnt; j += 4){
      int sA = __shfl(myE, j,   64);
      int sB = __shfl(myE, j+1, 64);
      int sC = __shfl(myE, j+2, 64);
      int sD = __shfl(myE, j+3, 64);
      float eA = als[sA*NH + h] + ad;
      float eB = als[sB*NH + h] + ad;
      float eC = als[sC*NH + h] + ad;
      float eD = als[sD*NH + h] + ad;
      eA = fmaxf(eA, 0.2f*eA); eB = fmaxf(eB, 0.2f*eB);
      eC = fmaxf(eC, 0.2f*eC); eD = fmaxf(eD, 0.2f*eD);
      float wA = __expf(eA), wB = __expf(eB), wC = __expf(eC), wD = __expf(eD);
      short8 vA = *(const short8*)(xp1 + (size_t)sA*F1 + f0);
      short8 vB = *(const short8*)(xp1 + (size_t)sB*F1 + f0);
      short8 vC = *(const short8*)(xp1 + (size_t)sC*F1 + f0);
      short8 vD = *(const short8*)(xp1 + (size_t)sD*F1 + f0);
      den += (wA + wB) + (wC + wD);
      #pragma unroll
      for (int jj = 0; jj < 8; jj++){
        accA[jj] = fmaf(wA, bf2f((ush)vA[jj]), accA[jj]);
        accB[jj] = fmaf(wB, bf2f((ush)vB[jj]), accB[jj]);
        accA[jj] = fmaf(wC, bf2f((ush)vC[jj]), accA[jj]);
        accB[jj] = fmaf(wD, bf2f((ush)vD[jj]), accB[jj]);
      }
    }
    for (; j < cnt; j++){
      int sA = __shfl(myE, j, 64);
      float eA = als[sA*NH + h] + ad;
      eA = fmaxf(eA, 0.2f*eA);
      float wA = __expf(eA);
      short8 vA = *(const short8*)(xp1 + (size_t)sA*F1 + f0);
      den += wA;
      #pragma unroll
      for (int jj = 0; jj < 8; jj++)
        accA[jj] = fmaf(wA, bf2f((ush)vA[jj]), accA[jj]);
    }
  }
  float inv = 1.f / den;
  #pragma unroll
  for (int jj = 0; jj < 8; jj++){
    float o = (accA[jj] + accB[jj])*inv + b1[f0 + jj];
    o = o > 0.f ? o : expm1f(o);
    h1[(size_t)w*F1 + f0 + jj] = f2bf(o);
  }
}

// ---- layer-2 aggregation (bf16 gather, in-loop weights) + fused classifier ----
__global__ __launch_bounds__(256) void k_agg2(const int* __restrict__ offs,
                                              const int* __restrict__ esrc,
                                              const ush* __restrict__ xp2,
                                              const float* __restrict__ als,
                                              const float* __restrict__ ald,
                                              const float* __restrict__ b2,
                                              const float* __restrict__ Wc1,
                                              const float* __restrict__ bc1,
                                              const float* __restrict__ Wc2,
                                              const float* __restrict__ bc2,
                                              float* __restrict__ out){
  int w = (blockIdx.x*256 + threadIdx.x) >> 6;
  int l = threadIdx.x & 63;
  if (w >= NN) return;
  float ad = ald[w];
  int s0 = offs[w], s1 = offs[w+1];
  float accA = 0.f, accB = 0.f, den = 0.f;

  for (int base = s0; base < s1; base += 64){
    int cnt = min(64, s1 - base);
    int myE = (base + l < s1) ? esrc[base + l] : 0;
    int j = 0;
    for (; j + 4 <= cnt; j += 4){
      int sA = __shfl(myE, j,   64);
      int sB = __shfl(myE, j+1, 64);
      int sC = __shfl(myE, j+2, 64);
      int sD = __shfl(myE, j+3, 64);
      float eA = als[sA] + ad, eB = als[sB] + ad, eC = als[sC] + ad, eD = als[sD] + ad;
      eA = fmaxf(eA, 0.2f*eA); eB = fmaxf(eB, 0.2f*eB);
      eC = fmaxf(eC, 0.2f*eC); eD = fmaxf(eD, 0.2f*eD);
      float wA = __expf(eA), wB = __expf(eB), wC = __expf(eC), wD = __expf(eD);
      float xA = bf2f(xp2[(size_t)sA*HID + l]);
      float xB = bf2f(xp2[(size_t)sB*HID + l]);
      float xC = bf2f(xp2[(size_t)sC*HID + l]);
      float xD = bf2f(xp2[(size_t)sD*HID + l]);
      den += (wA + wB) + (wC + wD);
      accA = fmaf(wA, xA, accA); accB = fmaf(wB, xB, accB);
      accA = fmaf(wC, xC, accA); accB = fmaf(wD, xD, accB);
    }
    for (; j < cnt; j++){
      int sA = __shfl(myE, j, 64);
      float eA = als[sA] + ad;
      eA = fmaxf(eA, 0.2f*eA);
      float wA = __expf(eA);
      den += wA;
      accA = fmaf(wA, bf2f(xp2[(size_t)sA*HID + l]), accA);
    }
  }
  float h2 = (accA + accB) / den + b2[l];
  float r = 0.f;
  #pragma unroll
  for (int k = 0; k < 64; k++){
    float hk = __shfl(h2, k, 64);
    r = fmaf(hk, Wc1[k*HID + l], r);
  }
  r += bc1[l];
  r = fmaxf(r, 0.f);
  float p0 = r * Wc2[l*2 + 0];
  float p1 = r * Wc2[l*2 + 1];
  #pragma unroll
  for (int o = 1; o < 64; o <<= 1){
    p0 += __shfl_xor(p0, o, 64);
    p1 += __shfl_xor(p1, o, 64);
  }
  if (l == 0){
    out[(size_t)w*2 + 0] = p0 + bc2[0];
    out[(size_t)w*2 + 1] = p1 + bc2[1];
  }
}

extern "C" void kernel_launch(void* const* d_in, const int* in_sizes, int n_in,
                              void* d_out, int out_size, void* d_ws, size_t ws_size,
                              hipStream_t stream){
  const float* x   = (const float*)d_in[0];
  const int*   ei  = (const int*)  d_in[1];
  const float* W1  = (const float*)d_in[2];
  const float* as1 = (const float*)d_in[3];
  const float* ad1 = (const float*)d_in[4];
  const float* b1  = (const float*)d_in[5];
  const float* W2  = (const float*)d_in[6];
  const float* as2 = (const float*)d_in[7];
  const float* ad2 = (const float*)d_in[8];
  const float* b2  = (const float*)d_in[9];
  const float* Wc1 = (const float*)d_in[10];
  const float* bc1 = (const float*)d_in[11];
  const float* Wc2 = (const float*)d_in[12];
  const float* bc2 = (const float*)d_in[13];
  float* out = (float*)d_out;

  char* p = (char*)d_ws; size_t off = 0;
  auto alloc = [&](size_t b){ void* r = p + off; off = (off + b + 255) & ~(size_t)255; return r; };
  ush* xpad = (ush*)alloc((size_t)NN*KP1*2);
  ush* W1t  = (ush*)alloc((size_t)512*KP1*2);
  ush* W2t  = (ush*)alloc((size_t)HID*F1*2);
  ush* xp1  = (ush*)alloc((size_t)NN*F1*2);
  ush* h1   = (ush*)alloc((size_t)NN*F1*2);
  ush* xp2  = (ush*)alloc((size_t)NN*HID*2);
  float* als1 = (float*)alloc((size_t)NN*NH*4);
  float* ald1 = (float*)alloc((size_t)NN*NH*4);
  float* als2 = (float*)alloc((size_t)NN*4);
  float* ald2 = (float*)alloc((size_t)NN*4);
  int* deg  = (int*)alloc((size_t)DEGPAD*4);
  int* cur  = (int*)alloc((size_t)NN*4);
  int* offs = (int*)alloc((size_t)(NN+1)*4);
  int* esrc = (int*)alloc((size_t)ET*4);

  hipMemsetAsync(deg, 0, (size_t)DEGPAD*4, stream);
  hipMemsetAsync(cur, 0, (size_t)NN*4, stream);

  const int T3 = NN*KP1 + 512*KP1 + HID*F1 + ET;
  k_prep_all<<<(T3 + 255)/256, 256, 0, stream>>>(x, W1, W2, ei, xpad, W1t, W2t, deg);
  k_scan<<<1, 1024, 0, stream>>>(deg, offs);
  k_scatter<<<(ET + 255)/256, 256, 0, stream>>>(ei, offs, cur, esrc);

  k_gemm1<<<dim3(391, 4), 256, 0, stream>>>(xpad, W1t, as1, ad1, xp1, als1, ald1);
  // agg1 split into thirds (node-partitioned; zero redundant work) so the
  // profiler's top-5 can surface the other kernels.
  k_agg1<<<4167, 256, 0, stream>>>(offs, esrc, xp1, als1, ald1, b1, h1, 0,     16667);
  k_agg1<<<4167, 256, 0, stream>>>(offs, esrc, xp1, als1, ald1, b1, h1, 16667, 16667);
  k_agg1<<<4167, 256, 0, stream>>>(offs, esrc, xp1, als1, ald1, b1, h1, 33334, 16666);

  k_gemm2<<<391, 256, 0, stream>>>(h1, W2t, as2, ad2, xp2, als2, ald2);
  k_agg2<<<12500, 256, 0, stream>>>(offs, esrc, xp2, als2, ald2, b2, Wc1, bc1, Wc2, bc2, out);
}

// Round 8
// 418.647 us; speedup vs baseline: 2.0045x; 1.0077x over previous
//
#include <hip/hip_runtime.h>

#define NN   50000
#define E0   800000
#define ET   850000
#define FIN  166
#define KP1  192
#define HID  64
#define NH   8
#define F1   512
#define SCHUNK 52
#define DEGPAD (1024*SCHUNK)

typedef __attribute__((ext_vector_type(8))) short short8;
typedef __attribute__((ext_vector_type(4))) float f32x4;
typedef __attribute__((ext_vector_type(4))) int int4v;
typedef unsigned short ush;

__device__ __forceinline__ float bf2f(unsigned short u){
  unsigned int x = ((unsigned int)u) << 16;
  return __builtin_bit_cast(float, x);
}
__device__ __forceinline__ unsigned short f2bf(float f){
  unsigned int x = __builtin_bit_cast(unsigned int, f);
  x += 0x7FFFu + ((x >> 16) & 1u);
  return (unsigned short)(x >> 16);
}

// ---- fused prep: pad/convert x, transpose+convert W1,W2, dst-degree histogram ----
__global__ __launch_bounds__(256) void k_prep_all(const float* __restrict__ x,
                                                  const float* __restrict__ W1,
                                                  const float* __restrict__ W2,
                                                  const int* __restrict__ ei,
                                                  ush* __restrict__ xpad,
                                                  ush* __restrict__ W1t,
                                                  ush* __restrict__ W2t,
                                                  int* __restrict__ deg){
  const int T0 = NN*KP1;
  const int T1 = T0 + 512*KP1;
  const int T2 = T1 + HID*F1;
  const int T3 = T2 + ET;
  int i = blockIdx.x*256 + threadIdx.x;
  if (i >= T3) return;
  if (i < T0){
    int n = i / KP1, k = i % KP1;
    xpad[i] = f2bf(k < FIN ? x[(size_t)n*FIN + k] : 0.f);
  } else if (i < T1){
    int j = i - T0; int col = j / KP1, k = j % KP1;
    W1t[j] = f2bf(k < FIN ? W1[(size_t)k*512 + col] : 0.f);
  } else if (i < T2){
    int j = i - T1; int col = j / F1, k = j % F1;
    W2t[j] = f2bf(W2[(size_t)k*HID + col]);
  } else {
    int e = i - T2;
    int dst = (e < E0) ? ei[E0 + e] : (e - E0);
    atomicAdd(&deg[dst], 1);
  }
}

// ---- exclusive scan of deg -> offs[NN+1], single block, int4 loads ----
__global__ __launch_bounds__(1024) void k_scan(const int* __restrict__ deg,
                                               int* __restrict__ offs){
  __shared__ int sums[1024];
  int t = threadIdx.x;
  int base = t * SCHUNK;
  int4v v[13];
  int loc = 0;
  #pragma unroll
  for (int c = 0; c < 13; c++){
    v[c] = *(const int4v*)(deg + base + c*4);
    loc += v[c].x + v[c].y + v[c].z + v[c].w;
  }
  sums[t] = loc; __syncthreads();
  for (int off = 1; off < 1024; off <<= 1){
    int s = (t >= off) ? sums[t - off] : 0;
    __syncthreads();
    sums[t] += s;
    __syncthreads();
  }
  int run = sums[t] - loc;
  #pragma unroll
  for (int c = 0; c < 13; c++){
    int i0 = base + c*4;
    if (i0 + 0 < NN) offs[i0 + 0] = run;  run += v[c].x;
    if (i0 + 1 < NN) offs[i0 + 1] = run;  run += v[c].y;
    if (i0 + 2 < NN) offs[i0 + 2] = run;  run += v[c].z;
    if (i0 + 3 < NN) offs[i0 + 3] = run;  run += v[c].w;
  }
  if (t == 1023) offs[NN] = sums[1023];
}

// ---- scatter edges into CSR-by-dst; record src AND dst ----
__global__ __launch_bounds__(256) void k_scatter(const int* __restrict__ ei,
                                                 const int* __restrict__ offs,
                                                 int* __restrict__ cur,
                                                 int* __restrict__ esrc,
                                                 int* __restrict__ edst){
  for (int e = blockIdx.x*256 + threadIdx.x; e < ET; e += gridDim.x*256){
    int src, dst;
    if (e < E0){ src = ei[e]; dst = ei[E0 + e]; }
    else       { src = e - E0; dst = src; }
    int pos = offs[dst] + atomicAdd(&cur[dst], 1);
    esrc[pos] = src;
    edst[pos] = dst;
  }
}

// ---- GEMM1: xpad[NN,192] @ W1t^T -> xp1 bf16 [NN,512]; fused per-head logits ----
__global__ __launch_bounds__(256) void k_gemm1(const ush* __restrict__ xpad,
                                               const ush* __restrict__ W1t,
                                               const float* __restrict__ a_s,
                                               const float* __restrict__ a_d,
                                               ush* __restrict__ xp1,
                                               float* __restrict__ als,
                                               float* __restrict__ ald){
  __shared__ ush As[128][40];
  __shared__ ush Bs[128][40];
  const int m0 = blockIdx.x*128, n0 = blockIdx.y*128;
  const int t = threadIdx.x, wid = t>>6, l = t&63;
  const int wr = wid>>1, wc = wid&1;
  const int lr = l&15, ksl = (l>>4)*8;
  const int srow = t>>1, sc = (t&1)*16;

  f32x4 acc[4][4];
  #pragma unroll
  for (int m = 0; m < 4; m++)
    #pragma unroll
    for (int n = 0; n < 4; n++)
      #pragma unroll
      for (int j = 0; j < 4; j++) acc[m][n][j] = 0.f;

  const int gr = m0 + srow;
  const ush* Ap = xpad + (size_t)gr*KP1 + sc;
  const ush* Bp = W1t + (size_t)(n0 + srow)*KP1 + sc;

  for (int s = 0; s < 6; s++){
    const int kk = s*32;
    short8 a0, a1;
    #pragma unroll
    for (int j = 0; j < 8; j++){ a0[j] = 0; a1[j] = 0; }
    if (gr < NN){ a0 = *(const short8*)(Ap + kk); a1 = *(const short8*)(Ap + kk + 8); }
    short8 b0 = *(const short8*)(Bp + kk);
    short8 b1 = *(const short8*)(Bp + kk + 8);
    *(short8*)&As[srow][sc]   = a0;
    *(short8*)&As[srow][sc+8] = a1;
    *(short8*)&Bs[srow][sc]   = b0;
    *(short8*)&Bs[srow][sc+8] = b1;
    __syncthreads();
    short8 af[4], bfr[4];
    #pragma unroll
    for (int m = 0; m < 4; m++) af[m]  = *(const short8*)&As[wr*64 + m*16 + lr][ksl];
    #pragma unroll
    for (int n = 0; n < 4; n++) bfr[n] = *(const short8*)&Bs[wc*64 + n*16 + lr][ksl];
    #pragma unroll
    for (int m = 0; m < 4; m++)
      #pragma unroll
      for (int n = 0; n < 4; n++)
        acc[m][n] = __builtin_amdgcn_mfma_f32_16x16x32_bf16(af[m], bfr[n], acc[m][n], 0, 0, 0);
    __syncthreads();
  }

  #pragma unroll
  for (int m = 0; m < 4; m++)
    #pragma unroll
    for (int n = 0; n < 4; n++)
      #pragma unroll
      for (int j = 0; j < 4; j++){
        int row = m0 + wr*64 + m*16 + (l>>4)*4 + j;
        int col = n0 + wc*64 + n*16 + lr;
        if (row < NN) xp1[(size_t)row*F1 + col] = f2bf(acc[m][n][j]);
      }

  const int head = blockIdx.y*2 + wc;
  float asv[4], adv[4];
  #pragma unroll
  for (int n = 0; n < 4; n++){
    asv[n] = a_s[head*64 + n*16 + lr];
    adv[n] = a_d[head*64 + n*16 + lr];
  }
  #pragma unroll
  for (int m = 0; m < 4; m++)
    #pragma unroll
    for (int j = 0; j < 4; j++){
      float ps = 0.f, pd = 0.f;
      #pragma unroll
      for (int n = 0; n < 4; n++){
        ps = fmaf(acc[m][n][j], asv[n], ps);
        pd = fmaf(acc[m][n][j], adv[n], pd);
      }
      #pragma unroll
      for (int o = 1; o < 16; o <<= 1){
        ps += __shfl_xor(ps, o, 64);
        pd += __shfl_xor(pd, o, 64);
      }
      if (lr == 0){
        int row = m0 + wr*64 + m*16 + (l>>4)*4 + j;
        if (row < NN){
          als[(size_t)row*NH + head] = fminf(fmaxf(ps, -30.f), 30.f);
          ald[(size_t)row*NH + head] = fminf(fmaxf(pd, -30.f), 30.f);
        }
      }
    }
}

// ---- GEMM2: h1[NN,512] @ W2t^T -> xp2 bf16 [NN,64]; fused logits (1 head) ----
__global__ __launch_bounds__(256) void k_gemm2(const ush* __restrict__ h1,
                                               const ush* __restrict__ W2t,
                                               const float* __restrict__ a_s,
                                               const float* __restrict__ a_d,
                                               ush* __restrict__ xp2,
                                               float* __restrict__ als,
                                               float* __restrict__ ald){
  __shared__ ush As[128][40];
  __shared__ ush Bs[64][40];
  const int m0 = blockIdx.x*128;
  const int t = threadIdx.x, wid = t>>6, l = t&63;
  const int lr = l&15, ksl = (l>>4)*8;
  const int srow = t>>1, sc = (t&1)*16;

  f32x4 acc[2][4];
  #pragma unroll
  for (int m = 0; m < 2; m++)
    #pragma unroll
    for (int n = 0; n < 4; n++)
      #pragma unroll
      for (int j = 0; j < 4; j++) acc[m][n][j] = 0.f;

  const int gr = m0 + srow;
  const ush* Ap = h1 + (size_t)gr*F1 + sc;
  const ush* Bp = W2t + (size_t)srow*F1 + sc;

  for (int s = 0; s < 16; s++){
    const int kk = s*32;
    short8 a0, a1;
    #pragma unroll
    for (int j = 0; j < 8; j++){ a0[j] = 0; a1[j] = 0; }
    if (gr < NN){ a0 = *(const short8*)(Ap + kk); a1 = *(const short8*)(Ap + kk + 8); }
    *(short8*)&As[srow][sc]   = a0;
    *(short8*)&As[srow][sc+8] = a1;
    if (t < 128){
      short8 b0 = *(const short8*)(Bp + kk);
      short8 b1 = *(const short8*)(Bp + kk + 8);
      *(short8*)&Bs[srow][sc]   = b0;
      *(short8*)&Bs[srow][sc+8] = b1;
    }
    __syncthreads();
    short8 af[2], bfr[4];
    #pragma unroll
    for (int m = 0; m < 2; m++) af[m]  = *(const short8*)&As[wid*32 + m*16 + lr][ksl];
    #pragma unroll
    for (int n = 0; n < 4; n++) bfr[n] = *(const short8*)&Bs[n*16 + lr][ksl];
    #pragma unroll
    for (int m = 0; m < 2; m++)
      #pragma unroll
      for (int n = 0; n < 4; n++)
        acc[m][n] = __builtin_amdgcn_mfma_f32_16x16x32_bf16(af[m], bfr[n], acc[m][n], 0, 0, 0);
    __syncthreads();
  }

  #pragma unroll
  for (int m = 0; m < 2; m++)
    #pragma unroll
    for (int n = 0; n < 4; n++)
      #pragma unroll
      for (int j = 0; j < 4; j++){
        int row = m0 + wid*32 + m*16 + (l>>4)*4 + j;
        int col = n*16 + lr;
        if (row < NN) xp2[(size_t)row*HID + col] = f2bf(acc[m][n][j]);
      }

  float asv[4], adv[4];
  #pragma unroll
  for (int n = 0; n < 4; n++){
    asv[n] = a_s[n*16 + lr];
    adv[n] = a_d[n*16 + lr];
  }
  #pragma unroll
  for (int m = 0; m < 2; m++)
    #pragma unroll
    for (int j = 0; j < 4; j++){
      float ps = 0.f, pd = 0.f;
      #pragma unroll
      for (int n = 0; n < 4; n++){
        ps = fmaf(acc[m][n][j], asv[n], ps);
        pd = fmaf(acc[m][n][j], adv[n], pd);
      }
      #pragma unroll
      for (int o = 1; o < 16; o <<= 1){
        ps += __shfl_xor(ps, o, 64);
        pd += __shfl_xor(pd, o, 64);
      }
      if (lr == 0){
        int row = m0 + wid*32 + m*16 + (l>>4)*4 + j;
        if (row < NN){
          als[row] = fminf(fmaxf(ps, -30.f), 30.f);
          ald[row] = fminf(fmaxf(pd, -30.f), 30.f);
        }
      }
    }
}

// ---- edge weights layer 2, CSR order (proven in round 5) ----
__global__ __launch_bounds__(256) void k_ew2(const int* __restrict__ esrc,
                                             const int* __restrict__ edst,
                                             const float* __restrict__ als,
                                             const float* __restrict__ ald,
                                             float* __restrict__ wt2){
  int pos = blockIdx.x*256 + threadIdx.x;
  if (pos >= ET) return;
  float v = als[esrc[pos]] + ald[edst[pos]];
  v = fmaxf(v, 0.2f*v);
  wt2[pos] = __expf(v);
}

// ---- layer-1 aggregation: wave per dst; chunked esrc via shfl; 4-way unroll ----
__global__ __launch_bounds__(256) void k_agg1(const int* __restrict__ offs,
                                              const int* __restrict__ esrc,
                                              const ush* __restrict__ xp1,
                                              const float* __restrict__ als,
                                              const float* __restrict__ ald,
                                              const float* __restrict__ b1,
                                              ush* __restrict__ h1){
  int w = (blockIdx.x*256 + threadIdx.x) >> 6;
  int l = threadIdx.x & 63;
  if (w >= NN) return;
  int h = l >> 3;
  int f0 = l * 8;
  float ad = ald[w*NH + h];
  int s0 = offs[w], s1 = offs[w+1];
  float accA[8], accB[8];
  #pragma unroll
  for (int j = 0; j < 8; j++){ accA[j] = 0.f; accB[j] = 0.f; }
  float den = 0.f;

  for (int base = s0; base < s1; base += 64){
    int cnt = min(64, s1 - base);
    int myE = (base + l < s1) ? esrc[base + l] : 0;
    int j = 0;
    for (; j + 4 <= cnt; j += 4){
      int sA = __shfl(myE, j,   64);
      int sB = __shfl(myE, j+1, 64);
      int sC = __shfl(myE, j+2, 64);
      int sD = __shfl(myE, j+3, 64);
      float eA = als[sA*NH + h] + ad;
      float eB = als[sB*NH + h] + ad;
      float eC = als[sC*NH + h] + ad;
      float eD = als[sD*NH + h] + ad;
      eA = fmaxf(eA, 0.2f*eA); eB = fmaxf(eB, 0.2f*eB);
      eC = fmaxf(eC, 0.2f*eC); eD = fmaxf(eD, 0.2f*eD);
      float wA = __expf(eA), wB = __expf(eB), wC = __expf(eC), wD = __expf(eD);
      short8 vA = *(const short8*)(xp1 + (size_t)sA*F1 + f0);
      short8 vB = *(const short8*)(xp1 + (size_t)sB*F1 + f0);
      short8 vC = *(const short8*)(xp1 + (size_t)sC*F1 + f0);
      short8 vD = *(const short8*)(xp1 + (size_t)sD*F1 + f0);
      den += (wA + wB) + (wC + wD);
      #pragma unroll
      for (int jj = 0; jj < 8; jj++){
        accA[jj] = fmaf(wA, bf2f((ush)vA[jj]), accA[jj]);
        accB[jj] = fmaf(wB, bf2f((ush)vB[jj]), accB[jj]);
        accA[jj] = fmaf(wC, bf2f((ush)vC[jj]), accA[jj]);
        accB[jj] = fmaf(wD, bf2f((ush)vD[jj]), accB[jj]);
      }
    }
    for (; j < cnt; j++){
      int sA = __shfl(myE, j, 64);
      float eA = als[sA*NH + h] + ad;
      eA = fmaxf(eA, 0.2f*eA);
      float wA = __expf(eA);
      short8 vA = *(const short8*)(xp1 + (size_t)sA*F1 + f0);
      den += wA;
      #pragma unroll
      for (int jj = 0; jj < 8; jj++)
        accA[jj] = fmaf(wA, bf2f((ush)vA[jj]), accA[jj]);
    }
  }
  float inv = 1.f / den;
  #pragma unroll
  for (int jj = 0; jj < 8; jj++){
    float o = (accA[jj] + accB[jj])*inv + b1[f0 + jj];
    o = o > 0.f ? o : expm1f(o);
    h1[(size_t)w*F1 + f0 + jj] = f2bf(o);
  }
}

// ---- layer-2 aggregation (precomputed wt2, shfl-broadcast, 8-deep) + classifier ----
__global__ __launch_bounds__(256) void k_agg2(const int* __restrict__ offs,
                                              const int* __restrict__ esrc,
                                              const ush* __restrict__ xp2,
                                              const float* __restrict__ wt2,
                                              const float* __restrict__ b2,
                                              const float* __restrict__ Wc1,
                                              const float* __restrict__ bc1,
                                              const float* __restrict__ Wc2,
                                              const float* __restrict__ bc2,
                                              float* __restrict__ out){
  int w = (blockIdx.x*256 + threadIdx.x) >> 6;
  int l = threadIdx.x & 63;
  if (w >= NN) return;
  int s0 = offs[w], s1 = offs[w+1];
  float accA = 0.f, accB = 0.f, den = 0.f;

  for (int base = s0; base < s1; base += 64){
    int cnt = min(64, s1 - base);
    bool ok = (base + l < s1);
    int   myE = ok ? esrc[base + l] : 0;
    float myW = ok ? wt2[base + l] : 0.f;
    int j = 0;
    for (; j + 8 <= cnt; j += 8){
      int sA = __shfl(myE, j,   64), sB = __shfl(myE, j+1, 64);
      int sC = __shfl(myE, j+2, 64), sD = __shfl(myE, j+3, 64);
      int sE = __shfl(myE, j+4, 64), sF = __shfl(myE, j+5, 64);
      int sG = __shfl(myE, j+6, 64), sH = __shfl(myE, j+7, 64);
      float wA = __shfl(myW, j,   64), wB = __shfl(myW, j+1, 64);
      float wC = __shfl(myW, j+2, 64), wD = __shfl(myW, j+3, 64);
      float wE = __shfl(myW, j+4, 64), wF = __shfl(myW, j+5, 64);
      float wG = __shfl(myW, j+6, 64), wH = __shfl(myW, j+7, 64);
      float xA = bf2f(xp2[(size_t)sA*HID + l]);
      float xB = bf2f(xp2[(size_t)sB*HID + l]);
      float xC = bf2f(xp2[(size_t)sC*HID + l]);
      float xD = bf2f(xp2[(size_t)sD*HID + l]);
      float xE = bf2f(xp2[(size_t)sE*HID + l]);
      float xF = bf2f(xp2[(size_t)sF*HID + l]);
      float xG = bf2f(xp2[(size_t)sG*HID + l]);
      float xH = bf2f(xp2[(size_t)sH*HID + l]);
      den += ((wA + wB) + (wC + wD)) + ((wE + wF) + (wG + wH));
      accA = fmaf(wA, xA, accA); accB = fmaf(wB, xB, accB);
      accA = fmaf(wC, xC, accA); accB = fmaf(wD, xD, accB);
      accA = fmaf(wE, xE, accA); accB = fmaf(wF, xF, accB);
      accA = fmaf(wG, xG, accA); accB = fmaf(wH, xH, accB);
    }
    for (; j < cnt; j++){
      int sA = __shfl(myE, j, 64);
      float wA = __shfl(myW, j, 64);
      den += wA;
      accA = fmaf(wA, bf2f(xp2[(size_t)sA*HID + l]), accA);
    }
  }
  float h2 = (accA + accB) / den + b2[l];
  float r = 0.f;
  #pragma unroll
  for (int k = 0; k < 64; k++){
    float hk = __shfl(h2, k, 64);
    r = fmaf(hk, Wc1[k*HID + l], r);
  }
  r += bc1[l];
  r = fmaxf(r, 0.f);
  float p0 = r * Wc2[l*2 + 0];
  float p1 = r * Wc2[l*2 + 1];
  #pragma unroll
  for (int o = 1; o < 64; o <<= 1){
    p0 += __shfl_xor(p0, o, 64);
    p1 += __shfl_xor(p1, o, 64);
  }
  if (l == 0){
    out[(size_t)w*2 + 0] = p0 + bc2[0];
    out[(size_t)w*2 + 1] = p1 + bc2[1];
  }
}

extern "C" void kernel_launch(void* const* d_in, const int* in_sizes, int n_in,
                              void* d_out, int out_size, void* d_ws, size_t ws_size,
                              hipStream_t stream){
  const float* x   = (const float*)d_in[0];
  const int*   ei  = (const int*)  d_in[1];
  const float* W1  = (const float*)d_in[2];
  const float* as1 = (const float*)d_in[3];
  const float* ad1 = (const float*)d_in[4];
  const float* b1  = (const float*)d_in[5];
  const float* W2  = (const float*)d_in[6];
  const float* as2 = (const float*)d_in[7];
  const float* ad2 = (const float*)d_in[8];
  const float* b2  = (const float*)d_in[9];
  const float* Wc1 = (const float*)d_in[10];
  const float* bc1 = (const float*)d_in[11];
  const float* Wc2 = (const float*)d_in[12];
  const float* bc2 = (const float*)d_in[13];
  float* out = (float*)d_out;

  char* p = (char*)d_ws; size_t off = 0;
  auto alloc = [&](size_t b){ void* r = p + off; off = (off + b + 255) & ~(size_t)255; return r; };
  ush* xpad = (ush*)alloc((size_t)NN*KP1*2);
  ush* W1t  = (ush*)alloc((size_t)512*KP1*2);
  ush* W2t  = (ush*)alloc((size_t)HID*F1*2);
  ush* xp1  = (ush*)alloc((size_t)NN*F1*2);
  ush* h1   = (ush*)alloc((size_t)NN*F1*2);
  ush* xp2  = (ush*)alloc((size_t)NN*HID*2);
  float* als1 = (float*)alloc((size_t)NN*NH*4);
  float* ald1 = (float*)alloc((size_t)NN*NH*4);
  float* als2 = (float*)alloc((size_t)NN*4);
  float* ald2 = (float*)alloc((size_t)NN*4);
  float* wt2  = (float*)alloc((size_t)ET*4);
  int* deg  = (int*)alloc((size_t)DEGPAD*4);
  int* cur  = (int*)alloc((size_t)NN*4);
  int* offs = (int*)alloc((size_t)(NN+1)*4);
  int* esrc = (int*)alloc((size_t)ET*4);
  int* edst = (int*)alloc((size_t)ET*4);

  hipMemsetAsync(deg, 0, (size_t)DEGPAD*4, stream);
  hipMemsetAsync(cur, 0, (size_t)NN*4, stream);

  const int T3 = NN*KP1 + 512*KP1 + HID*F1 + ET;
  k_prep_all<<<(T3 + 255)/256, 256, 0, stream>>>(x, W1, W2, ei, xpad, W1t, W2t, deg);
  k_scan<<<1, 1024, 0, stream>>>(deg, offs);
  k_scatter<<<(ET + 255)/256, 256, 0, stream>>>(ei, offs, cur, esrc, edst);

  k_gemm1<<<dim3(391, 4), 256, 0, stream>>>(xpad, W1t, as1, ad1, xp1, als1, ald1);
  k_agg1<<<12500, 256, 0, stream>>>(offs, esrc, xp1, als1, ald1, b1, h1);

  k_gemm2<<<391, 256, 0, stream>>>(h1, W2t, as2, ad2, xp2, als2, ald2);
  k_ew2<<<(ET + 255)/256, 256, 0, stream>>>(esrc, edst, als2, ald2, wt2);
  k_agg2<<<12500, 256, 0, stream>>>(offs, esrc, xp2, wt2, b2, Wc1, bc1, Wc2, bc2, out);
}